// Round 12
// baseline (3018.091 us; speedup 1.0000x reference)
//
#include <hip/hip_runtime.h>

using u32 = unsigned int;
using u64 = unsigned long long;
using bf16x8 = __attribute__((ext_vector_type(8))) short;
using f32x4  = __attribute__((ext_vector_type(4))) float;

// Problem constants
#define BB_ 64
#define TT_ 512
#define II_ 1024
#define HH_ 1024
#define NSCAN_BLOCKS 256   // 8 domains (8 batch rows, nominal XCD) x 32 j-blocks

__device__ __forceinline__ unsigned short bf16rne(float f) {
  u32 u = __float_as_uint(f);
  return (unsigned short)((u + 0x7FFFu + ((u >> 16) & 1u)) >> 16);
}
__device__ __forceinline__ u32 pk2(float a, float b) {
  u32 ua = __float_as_uint(a), ub = __float_as_uint(b);
  u32 lo = (ua + 0x7FFFu + ((ua >> 16) & 1u)) >> 16;
  u32 hi = (ub + 0x7FFFu + ((ub >> 16) & 1u)) & 0xFFFF0000u;
  return lo | hi;
}
__device__ __forceinline__ void gll16(const void* g, void* s) {
  __builtin_amdgcn_global_load_lds(
      (const __attribute__((address_space(1))) u32*)g,
      (__attribute__((address_space(3))) u32*)s, 16, 0, 0);
}
// fast tanh: 1 - 2/(exp2(2*log2e*x)+1); |err| < 1e-6, exact +-1 saturation
__device__ __forceinline__ float tanhfast(float x) {
  float e = __builtin_amdgcn_exp2f(x * 2.885390081777927f);
  return 1.0f - 2.0f / (e + 1.0f);
}

__device__ __forceinline__ void cvt4(const float* __restrict__ s, unsigned short* __restrict__ d, long long g) {
  float4 v = ((const float4*)s)[g];
  ushort4 o;
  o.x = bf16rne(v.x); o.y = bf16rne(v.y); o.z = bf16rne(v.z); o.w = bf16rne(v.w);
  ((ushort4*)d)[g] = o;
}

// ---------------------------------------------------------------------------
// k_convert: bf16 copies of x / W_ih / [W_hh1;W_hh2]; tagged h0 (bf16<<16|0)
// seeded into BOTH hL and hM parity-slot 0 via relaxed AGENT atomics (LLC
// only). Replay residue anywhere is tag-mismatched or bit-identical
// (determinism) -> safe. Full rewrite each launch -> graph-replay safe.
// ---------------------------------------------------------------------------
__global__ void k_convert(const float* __restrict__ x, const float* __restrict__ h0,
                          const float* __restrict__ Wih, const float* __restrict__ Wh1,
                          const float* __restrict__ Wh2,
                          unsigned short* __restrict__ xb, unsigned short* __restrict__ Wihb,
                          unsigned short* __restrict__ Wcatb, u32* __restrict__ hL,
                          u32* __restrict__ hM, int do_x) {
  const long long NWI = (long long)HH_ * II_ / 4;
  const long long NH0 = (long long)BB_ * HH_ / 4;   // float4 granules
  const long long NX  = do_x ? ((long long)BB_ * TT_ * II_ / 4) : 0;
  const long long total = 3 * NWI + NH0 + NX;
  for (long long g = (long long)blockIdx.x * blockDim.x + threadIdx.x; g < total;
       g += (long long)gridDim.x * blockDim.x) {
    if (g < NWI) {
      cvt4(Wih, Wihb, g);
    } else if (g < 2 * NWI) {
      cvt4(Wh1, Wcatb, g - NWI);
    } else if (g < 3 * NWI) {
      cvt4(Wh2, Wcatb + (long long)HH_ * II_, g - 2 * NWI);
    } else if (g < 3 * NWI + NH0) {
      long long gg = g - 3 * NWI;
      float4 v = ((const float4*)h0)[gg];
      u32 wv[4];
      wv[0] = (u32)bf16rne(v.x) << 16;  // tag 0
      wv[1] = (u32)bf16rne(v.y) << 16;
      wv[2] = (u32)bf16rne(v.z) << 16;
      wv[3] = (u32)bf16rne(v.w) << 16;
      u64 base = (u64)gg * 4;
#pragma unroll
      for (int i = 0; i < 4; ++i) {
        __hip_atomic_store(hL + base + i, wv[i], __ATOMIC_RELAXED, __HIP_MEMORY_SCOPE_AGENT);
        __hip_atomic_store(hM + base + i, wv[i], __ATOMIC_RELAXED, __HIP_MEMORY_SCOPE_AGENT);
      }
    } else {
      cvt4(x, xb, g - (3 * NWI + NH0));
    }
  }
}

// ---------------------------------------------------------------------------
// k_gemm: xp = x @ Wih^T + b_ih, written into d_out (NT stores). Unchanged.
// ---------------------------------------------------------------------------
template <bool XB>
__global__ __launch_bounds__(256) void k_gemm(const unsigned short* __restrict__ xbg,
                                              const float* __restrict__ xf,
                                              const unsigned short* __restrict__ Wb,
                                              const float* __restrict__ bias,
                                              float* __restrict__ C) {
  __shared__ __align__(16) unsigned short ldsA[128 * 64];
  __shared__ __align__(16) unsigned short ldsB[128 * 64];
  const int tid = threadIdx.x;
  const int w = tid >> 6, l = tid & 63;
  const int lr = l & 15, lk = l >> 4;
  const int n0 = (blockIdx.x & 7) * 128;
  const int m0 = (blockIdx.x >> 3) * 128;
  const int mbase = (w >> 1) * 64, nbase = (w & 1) * 64;

  f32x4 acc[4][4] = {};

  for (int kb = 0; kb < 16; ++kb) {
    const int k0 = kb * 64;
#pragma unroll
    for (int r = 0; r < 4; ++r) {
      int tb = r * 4096 + w * 1024 + l * 16;
      int row = tb >> 7;
      int p = (tb >> 4) & 7;
      int c = p ^ (row & 7);
      gll16(Wb + (u64)(n0 + row) * II_ + k0 + c * 8,
            (char*)ldsB + r * 4096 + w * 1024);
    }
    if constexpr (XB) {
#pragma unroll
      for (int r = 0; r < 4; ++r) {
        int tb = r * 4096 + w * 1024 + l * 16;
        int row = tb >> 7;
        int p = (tb >> 4) & 7;
        int c = p ^ (row & 7);
        gll16(xbg + (u64)(m0 + row) * II_ + k0 + c * 8,
              (char*)ldsA + r * 4096 + w * 1024);
      }
    } else {
      const int r = tid >> 1, ch = tid & 1;
      const float* gs = xf + (u64)(m0 + r) * II_ + k0 + ch * 32;
      float4 v[8];
#pragma unroll
      for (int q = 0; q < 8; ++q) v[q] = ((const float4*)gs)[q];
#pragma unroll
      for (int q = 0; q < 4; ++q) {
        int c = ch * 4 + q;
        int p = c ^ (r & 7);
        uint4 pk;
        pk.x = pk2(v[2 * q].x, v[2 * q].y);
        pk.y = pk2(v[2 * q].z, v[2 * q].w);
        pk.z = pk2(v[2 * q + 1].x, v[2 * q + 1].y);
        pk.w = pk2(v[2 * q + 1].z, v[2 * q + 1].w);
        *(uint4*)((char*)ldsA + r * 128 + p * 16) = pk;
      }
    }
    __syncthreads();

    bf16x8 a[4][2], b[4][2];
#pragma unroll
    for (int mt = 0; mt < 4; ++mt) {
      int row = mbase + mt * 16 + lr;
#pragma unroll
      for (int kk = 0; kk < 2; ++kk) {
        int c = kk * 4 + lk, p = c ^ (row & 7);
        a[mt][kk] = *(const bf16x8*)((const char*)ldsA + row * 128 + p * 16);
      }
    }
#pragma unroll
    for (int nt = 0; nt < 4; ++nt) {
      int row = nbase + nt * 16 + lr;
#pragma unroll
      for (int kk = 0; kk < 2; ++kk) {
        int c = kk * 4 + lk, p = c ^ (row & 7);
        b[nt][kk] = *(const bf16x8*)((const char*)ldsB + row * 128 + p * 16);
      }
    }
#pragma unroll
    for (int kk = 0; kk < 2; ++kk)
#pragma unroll
      for (int mt = 0; mt < 4; ++mt)
#pragma unroll
        for (int nt = 0; nt < 4; ++nt)
          acc[mt][nt] = __builtin_amdgcn_mfma_f32_16x16x32_bf16(a[mt][kk], b[nt][kk], acc[mt][nt], 0, 0, 0);
    __syncthreads();
  }

  float bn[4];
#pragma unroll
  for (int nt = 0; nt < 4; ++nt) bn[nt] = bias[n0 + nbase + nt * 16 + lr];
#pragma unroll
  for (int mt = 0; mt < 4; ++mt) {
#pragma unroll
    for (int i = 0; i < 4; ++i) {
      int m = m0 + mbase + mt * 16 + lk * 4 + i;
      float* cr = C + (u64)m * HH_ + n0 + nbase + lr;
#pragma unroll
      for (int nt = 0; nt < 4; ++nt)
        __builtin_nontemporal_store(acc[mt][nt][i] + bn[nt], cr + nt * 16);
    }
  }
}

// ---------------------------------------------------------------------------
// k_scan v12 = v11 with the compile fix: wq fences are now
//   asm volatile("s_waitcnt vmcnt(0)") + __builtin_amdgcn_sched_barrier(0)
// (guide rule #18 idiom: the sched_barrier stops hipcc from hoisting the
// register-only tag checks above the waitcnt; tied 16-operand fences don't
// compile). Everything else identical to v11:
// 8 domains (nominal XCD) x 32 j-blocks; AGPR-pinned weights; tagged words
// (bf16<<16|step) to hL (plain store -> producer-XCD L2) + hM mirror (agent
// atomic -> LLC, always fresh); consumer sc0 loads + per-chunk tag equality,
// masked retry, every 4th round reads the mirror. Publish is fire-and-forget
// (no ack, no flag, no barrier). Tags + determinism make ALL stale-cache /
// replay-residue scenarios either detected or bit-identical-correct.
// ---------------------------------------------------------------------------
__global__ __launch_bounds__(256, 1) void k_scan(float* __restrict__ out, const float* __restrict__ h0,
                                                 const float* __restrict__ b1, const float* __restrict__ b2,
                                                 const unsigned short* __restrict__ Wcat,
                                                 u32* __restrict__ hL, u32* __restrict__ hM) {
  __shared__ float part[16 * 4 * 65];  // [(w*4+nt)*4+i][l] stride 65
  const int tid = threadIdx.x, w = tid >> 6, l = tid & 63;
  const int lr = l & 15, lk = l >> 4;
  const int g = blockIdx.x & 7, r = blockIdx.x >> 3;
  const int bb = g * 8, jb = r * 32;
  const int koff = w * 256;

  // --- weights -> 128 AGPRs (r9-proven) ---
  bf16x8 wt[4][8];
#pragma unroll
  for (int nt = 0; nt < 4; ++nt) {
    int nrow = (nt < 2) ? (jb + nt * 16 + lr) : (HH_ + jb + (nt - 2) * 16 + lr);
    const unsigned short* wr = Wcat + (u64)nrow * HH_ + koff + lk * 8;
#pragma unroll
    for (int kk = 0; kk < 8; ++kk) wt[nt][kk] = *(const bf16x8*)(wr + kk * 32);
  }

  // --- epilogue identity: batch row b = tid>>5 (0..7), col cl = tid&31 ---
  const int b = tid >> 5, cl = tid & 31;
  const int grow = bb + b, gcol = jb + cl;
  const float bv1 = b1[gcol], bv2 = b2[gcol];
  float hold = h0[(u64)grow * HH_ + gcol];
  float* outp = out + (u64)grow * TT_ * HH_ + gcol;
  const u32 stIdx = (u32)grow * HH_ + gcol;                       // store word
  const u32 ldIdx = (u32)(bb + (lr & 7)) * HH_ + koff + lk * 8;   // load base
  const bool act = lr < 8;

  for (int t = 0; t < TT_; ++t) {
    float xpv = outp[(u64)t * HH_];  // xp prefetch (hides under tag wait)

    // ---- two-tier tagged load: 8 chunks x 8 words per active lane ----
    const u32 slotR = (u32)(t & 1) * (BB_ * HH_);
    const u32* pL = hL + slotR + ldIdx;
    const u32* pM = hM + slotR + ldIdx;
    const u32 expt = (u32)t;
    uint4 wq[16] = {};
    if (act) {
#pragma unroll
      for (int kk = 0; kk < 8; ++kk) {
        const u32* pc = pL + kk * 32;
        asm volatile("global_load_dwordx4 %0, %1, off sc0"
                     : "=&v"(wq[2 * kk]) : "v"(pc) : "memory");
        asm volatile("global_load_dwordx4 %0, %1, off offset:16 sc0"
                     : "=&v"(wq[2 * kk + 1]) : "v"(pc) : "memory");
      }
    }
    asm volatile("s_waitcnt vmcnt(0)" ::: "memory");
    __builtin_amdgcn_sched_barrier(0);

    u32 gm = 0;
    if (act) {
#pragma unroll
      for (int kk = 0; kk < 8; ++kk) {
        u32 bad = (wq[2 * kk].x ^ expt) | (wq[2 * kk].y ^ expt) |
                  (wq[2 * kk].z ^ expt) | (wq[2 * kk].w ^ expt) |
                  (wq[2 * kk + 1].x ^ expt) | (wq[2 * kk + 1].y ^ expt) |
                  (wq[2 * kk + 1].z ^ expt) | (wq[2 * kk + 1].w ^ expt);
        gm |= (u32)((bad & 0xFFFFu) != 0) << kk;
      }
    }
    int round = 0;
    while (__any((int)gm)) {
      ++round;
      const bool esc = (round & 3) == 0;  // every 4th round: LLC mirror
#pragma unroll
      for (int kk = 0; kk < 8; ++kk) {
        if (gm & (1u << kk)) {
          if (esc) {
            const u32* pm = pM + kk * 32;
            u32 m0 = __hip_atomic_load(pm + 0, __ATOMIC_RELAXED, __HIP_MEMORY_SCOPE_AGENT);
            u32 m1 = __hip_atomic_load(pm + 1, __ATOMIC_RELAXED, __HIP_MEMORY_SCOPE_AGENT);
            u32 m2 = __hip_atomic_load(pm + 2, __ATOMIC_RELAXED, __HIP_MEMORY_SCOPE_AGENT);
            u32 m3 = __hip_atomic_load(pm + 3, __ATOMIC_RELAXED, __HIP_MEMORY_SCOPE_AGENT);
            u32 m4 = __hip_atomic_load(pm + 4, __ATOMIC_RELAXED, __HIP_MEMORY_SCOPE_AGENT);
            u32 m5 = __hip_atomic_load(pm + 5, __ATOMIC_RELAXED, __HIP_MEMORY_SCOPE_AGENT);
            u32 m6 = __hip_atomic_load(pm + 6, __ATOMIC_RELAXED, __HIP_MEMORY_SCOPE_AGENT);
            u32 m7 = __hip_atomic_load(pm + 7, __ATOMIC_RELAXED, __HIP_MEMORY_SCOPE_AGENT);
            wq[2 * kk]     = make_uint4(m0, m1, m2, m3);
            wq[2 * kk + 1] = make_uint4(m4, m5, m6, m7);
          } else {
            const u32* pc = pL + kk * 32;
            asm volatile("global_load_dwordx4 %0, %1, off sc0"
                         : "=&v"(wq[2 * kk]) : "v"(pc) : "memory");
            asm volatile("global_load_dwordx4 %0, %1, off offset:16 sc0"
                         : "=&v"(wq[2 * kk + 1]) : "v"(pc) : "memory");
          }
        }
      }
      asm volatile("s_waitcnt vmcnt(0)" ::: "memory");
      __builtin_amdgcn_sched_barrier(0);
#pragma unroll
      for (int kk = 0; kk < 8; ++kk) {
        if (gm & (1u << kk)) {
          u32 bad = (wq[2 * kk].x ^ expt) | (wq[2 * kk].y ^ expt) |
                    (wq[2 * kk].z ^ expt) | (wq[2 * kk].w ^ expt) |
                    (wq[2 * kk + 1].x ^ expt) | (wq[2 * kk + 1].y ^ expt) |
                    (wq[2 * kk + 1].z ^ expt) | (wq[2 * kk + 1].w ^ expt);
          if (!(bad & 0xFFFFu)) gm &= ~(1u << kk);
        }
      }
    }

    // ---- unpack payload (high halves) -> A-frags; rows 8..15 zero; MFMA ----
    f32x4 acc[4] = {};
#pragma unroll
    for (int kk = 0; kk < 8; ++kk) {
      union { u32 u[4]; bf16x8 v; } au;
      if (act) {
        au.u[0] = __builtin_amdgcn_perm(wq[2 * kk].y, wq[2 * kk].x, 0x07060302);
        au.u[1] = __builtin_amdgcn_perm(wq[2 * kk].w, wq[2 * kk].z, 0x07060302);
        au.u[2] = __builtin_amdgcn_perm(wq[2 * kk + 1].y, wq[2 * kk + 1].x, 0x07060302);
        au.u[3] = __builtin_amdgcn_perm(wq[2 * kk + 1].w, wq[2 * kk + 1].z, 0x07060302);
      } else {
        au.u[0] = au.u[1] = au.u[2] = au.u[3] = 0u;
      }
#pragma unroll
      for (int nt = 0; nt < 4; ++nt)
        asm("v_mfma_f32_16x16x32_bf16 %0, %1, %2, %0"
            : "+v"(acc[nt]) : "v"(au.v), "a"(wt[nt][kk]));
    }
    asm volatile("s_nop 7\n\ts_nop 7\n\ts_nop 7"
                 : "+v"(acc[0]), "+v"(acc[1]), "+v"(acc[2]), "+v"(acc[3]));

    // ---- K-partials to LDS; combine; gates ----
#pragma unroll
    for (int nt = 0; nt < 4; ++nt)
#pragma unroll
      for (int i = 0; i < 4; ++i)
        part[((w * 4 + nt) * 4 + i) * 65 + l] = acc[nt][i];
    __syncthreads();

    const int nt1 = cl >> 4, jl = cl & 15;
    const int lidx = (b >> 2) * 16 + jl, ridx = b & 3;
    float v1 = 0.f, v2 = 0.f;
#pragma unroll
    for (int ww = 0; ww < 4; ++ww) {
      v1 += part[((ww * 4 + nt1) * 4 + ridx) * 65 + lidx];
      v2 += part[((ww * 4 + 2 + nt1) * 4 + ridx) * 65 + lidx];
    }
    float t1 = tanhfast(v1 + xpv + bv1);
    float t2 = tanhfast(v2 + xpv + bv2);
    float hn = t1 + hold * (t2 - t1);  // (1-h)*v1 + h*v2
    hold = hn;

    // ---- publish: tagged word to local (plain) + mirror (agent atomic) ----
    if (t < TT_ - 1) {
      u32 word = ((u32)bf16rne(hn) << 16) | (u32)(t + 1);
      u32 so = (u32)((t + 1) & 1) * (BB_ * HH_) + stIdx;
      hL[so] = word;  // plain store -> producer-XCD L2 (fast local path)
      __hip_atomic_store(hM + so, word, __ATOMIC_RELAXED, __HIP_MEMORY_SCOPE_AGENT);
    } else {
      out[(u64)BB_ * TT_ * HH_ + (u64)grow * HH_ + gcol] = hn;
    }
    outp[(u64)t * HH_] = hn;    // trajectory (off the handshake)
    __syncthreads();            // part[] WAR for next step
  }
}

// ---------------------------------------------------------------------------
extern "C" void kernel_launch(void* const* d_in, const int* in_sizes, int n_in,
                              void* d_out, int out_size, void* d_ws, size_t ws_size,
                              hipStream_t stream) {
  const float* x    = (const float*)d_in[0];
  const float* h0   = (const float*)d_in[1];
  const float* Wih  = (const float*)d_in[2];
  const float* bih  = (const float*)d_in[3];
  const float* Whh1 = (const float*)d_in[4];
  const float* bhh1 = (const float*)d_in[5];
  const float* Whh2 = (const float*)d_in[6];
  const float* bhh2 = (const float*)d_in[7];
  float* out = (float*)d_out;

  char* ws = (char*)d_ws;
  unsigned short* Wihb  = (unsigned short*)(ws + 0);          //  2 MiB
  unsigned short* Wcatb = (unsigned short*)(ws + 2097152);    //  4 MiB
  u32*            hL    = (u32*)(ws + 6291456);               //  512 KiB (local tier)
  u32*            hM    = (u32*)(ws + 6815744);               //  512 KiB (LLC mirror)
  unsigned short* xb    = (unsigned short*)(ws + 7340032);    //  64 MiB
  const bool fastx = ws_size >= 74448896ULL;

  hipLaunchKernelGGL(k_convert, dim3(2048), dim3(256), 0, stream,
                     x, h0, Wih, Whh1, Whh2, xb, Wihb, Wcatb, hL, hM, (int)fastx);
  if (fastx)
    hipLaunchKernelGGL((k_gemm<true>), dim3(2048), dim3(256), 0, stream,
                       xb, (const float*)nullptr, Wihb, bih, out);
  else
    hipLaunchKernelGGL((k_gemm<false>), dim3(2048), dim3(256), 0, stream,
                       (const unsigned short*)nullptr, x, Wihb, bih, out);
  hipLaunchKernelGGL(k_scan, dim3(NSCAN_BLOCKS), dim3(256), 0, stream,
                     out, h0, bhh1, bhh2, Wcatb, hL, hM);
}

// Round 13
// 2321.189 us; speedup vs baseline: 1.3002x; 1.3002x over previous
//
#include <hip/hip_runtime.h>

using u32 = unsigned int;
using u64 = unsigned long long;
using bf16x8 = __attribute__((ext_vector_type(8))) short;
using f32x4  = __attribute__((ext_vector_type(4))) float;

// Problem constants
#define BB_ 64
#define TT_ 512
#define II_ 1024
#define HH_ 1024
#define NSCAN_BLOCKS 256   // 8 domains (8 batch rows, nominal XCD) x 32 j-blocks

__device__ __forceinline__ unsigned short bf16rne(float f) {
  u32 u = __float_as_uint(f);
  return (unsigned short)((u + 0x7FFFu + ((u >> 16) & 1u)) >> 16);
}
__device__ __forceinline__ u32 pk2(float a, float b) {
  u32 ua = __float_as_uint(a), ub = __float_as_uint(b);
  u32 lo = (ua + 0x7FFFu + ((ua >> 16) & 1u)) >> 16;
  u32 hi = (ub + 0x7FFFu + ((ub >> 16) & 1u)) & 0xFFFF0000u;
  return lo | hi;
}
__device__ __forceinline__ void gll16(const void* g, void* s) {
  __builtin_amdgcn_global_load_lds(
      (const __attribute__((address_space(1))) u32*)g,
      (__attribute__((address_space(3))) u32*)s, 16, 0, 0);
}
// fast tanh: 1 - 2/(exp2(2*log2e*x)+1); |err| < 1e-6, exact +-1 saturation
__device__ __forceinline__ float tanhfast(float x) {
  float e = __builtin_amdgcn_exp2f(x * 2.885390081777927f);
  return 1.0f - 2.0f / (e + 1.0f);
}

__device__ __forceinline__ void cvt4(const float* __restrict__ s, unsigned short* __restrict__ d, long long g) {
  float4 v = ((const float4*)s)[g];
  ushort4 o;
  o.x = bf16rne(v.x); o.y = bf16rne(v.y); o.z = bf16rne(v.z); o.w = bf16rne(v.w);
  ((ushort4*)d)[g] = o;
}

// ---------------------------------------------------------------------------
// k_convert: bf16 copies of x / W_ih / [W_hh1;W_hh2]; tagged h0 (bf16<<16|0)
// seeded into BOTH hL and hM parity-slot 0 via relaxed AGENT atomics. Replay
// residue anywhere is tag-mismatched or bit-identical (determinism) -> safe.
// ---------------------------------------------------------------------------
__global__ void k_convert(const float* __restrict__ x, const float* __restrict__ h0,
                          const float* __restrict__ Wih, const float* __restrict__ Wh1,
                          const float* __restrict__ Wh2,
                          unsigned short* __restrict__ xb, unsigned short* __restrict__ Wihb,
                          unsigned short* __restrict__ Wcatb, u32* __restrict__ hL,
                          u32* __restrict__ hM, int do_x) {
  const long long NWI = (long long)HH_ * II_ / 4;
  const long long NH0 = (long long)BB_ * HH_ / 4;   // float4 granules
  const long long NX  = do_x ? ((long long)BB_ * TT_ * II_ / 4) : 0;
  const long long total = 3 * NWI + NH0 + NX;
  for (long long g = (long long)blockIdx.x * blockDim.x + threadIdx.x; g < total;
       g += (long long)gridDim.x * blockDim.x) {
    if (g < NWI) {
      cvt4(Wih, Wihb, g);
    } else if (g < 2 * NWI) {
      cvt4(Wh1, Wcatb, g - NWI);
    } else if (g < 3 * NWI) {
      cvt4(Wh2, Wcatb + (long long)HH_ * II_, g - 2 * NWI);
    } else if (g < 3 * NWI + NH0) {
      long long gg = g - 3 * NWI;
      float4 v = ((const float4*)h0)[gg];
      u32 wv[4];
      wv[0] = (u32)bf16rne(v.x) << 16;  // tag 0
      wv[1] = (u32)bf16rne(v.y) << 16;
      wv[2] = (u32)bf16rne(v.z) << 16;
      wv[3] = (u32)bf16rne(v.w) << 16;
      u64 base = (u64)gg * 4;
#pragma unroll
      for (int i = 0; i < 4; ++i) {
        __hip_atomic_store(hL + base + i, wv[i], __ATOMIC_RELAXED, __HIP_MEMORY_SCOPE_AGENT);
        __hip_atomic_store(hM + base + i, wv[i], __ATOMIC_RELAXED, __HIP_MEMORY_SCOPE_AGENT);
      }
    } else {
      cvt4(x, xb, g - (3 * NWI + NH0));
    }
  }
}

// ---------------------------------------------------------------------------
// k_gemm: xp = x @ Wih^T + b_ih, written into d_out (NT stores). Unchanged.
// ---------------------------------------------------------------------------
template <bool XB>
__global__ __launch_bounds__(256) void k_gemm(const unsigned short* __restrict__ xbg,
                                              const float* __restrict__ xf,
                                              const unsigned short* __restrict__ Wb,
                                              const float* __restrict__ bias,
                                              float* __restrict__ C) {
  __shared__ __align__(16) unsigned short ldsA[128 * 64];
  __shared__ __align__(16) unsigned short ldsB[128 * 64];
  const int tid = threadIdx.x;
  const int w = tid >> 6, l = tid & 63;
  const int lr = l & 15, lk = l >> 4;
  const int n0 = (blockIdx.x & 7) * 128;
  const int m0 = (blockIdx.x >> 3) * 128;
  const int mbase = (w >> 1) * 64, nbase = (w & 1) * 64;

  f32x4 acc[4][4] = {};

  for (int kb = 0; kb < 16; ++kb) {
    const int k0 = kb * 64;
#pragma unroll
    for (int r = 0; r < 4; ++r) {
      int tb = r * 4096 + w * 1024 + l * 16;
      int row = tb >> 7;
      int p = (tb >> 4) & 7;
      int c = p ^ (row & 7);
      gll16(Wb + (u64)(n0 + row) * II_ + k0 + c * 8,
            (char*)ldsB + r * 4096 + w * 1024);
    }
    if constexpr (XB) {
#pragma unroll
      for (int r = 0; r < 4; ++r) {
        int tb = r * 4096 + w * 1024 + l * 16;
        int row = tb >> 7;
        int p = (tb >> 4) & 7;
        int c = p ^ (row & 7);
        gll16(xbg + (u64)(m0 + row) * II_ + k0 + c * 8,
              (char*)ldsA + r * 4096 + w * 1024);
      }
    } else {
      const int r = tid >> 1, ch = tid & 1;
      const float* gs = xf + (u64)(m0 + r) * II_ + k0 + ch * 32;
      float4 v[8];
#pragma unroll
      for (int q = 0; q < 8; ++q) v[q] = ((const float4*)gs)[q];
#pragma unroll
      for (int q = 0; q < 4; ++q) {
        int c = ch * 4 + q;
        int p = c ^ (r & 7);
        uint4 pk;
        pk.x = pk2(v[2 * q].x, v[2 * q].y);
        pk.y = pk2(v[2 * q].z, v[2 * q].w);
        pk.z = pk2(v[2 * q + 1].x, v[2 * q + 1].y);
        pk.w = pk2(v[2 * q + 1].z, v[2 * q + 1].w);
        *(uint4*)((char*)ldsA + r * 128 + p * 16) = pk;
      }
    }
    __syncthreads();

    bf16x8 a[4][2], b[4][2];
#pragma unroll
    for (int mt = 0; mt < 4; ++mt) {
      int row = mbase + mt * 16 + lr;
#pragma unroll
      for (int kk = 0; kk < 2; ++kk) {
        int c = kk * 4 + lk, p = c ^ (row & 7);
        a[mt][kk] = *(const bf16x8*)((const char*)ldsA + row * 128 + p * 16);
      }
    }
#pragma unroll
    for (int nt = 0; nt < 4; ++nt) {
      int row = nbase + nt * 16 + lr;
#pragma unroll
      for (int kk = 0; kk < 2; ++kk) {
        int c = kk * 4 + lk, p = c ^ (row & 7);
        b[nt][kk] = *(const bf16x8*)((const char*)ldsB + row * 128 + p * 16);
      }
    }
#pragma unroll
    for (int kk = 0; kk < 2; ++kk)
#pragma unroll
      for (int mt = 0; mt < 4; ++mt)
#pragma unroll
        for (int nt = 0; nt < 4; ++nt)
          acc[mt][nt] = __builtin_amdgcn_mfma_f32_16x16x32_bf16(a[mt][kk], b[nt][kk], acc[mt][nt], 0, 0, 0);
    __syncthreads();
  }

  float bn[4];
#pragma unroll
  for (int nt = 0; nt < 4; ++nt) bn[nt] = bias[n0 + nbase + nt * 16 + lr];
#pragma unroll
  for (int mt = 0; mt < 4; ++mt) {
#pragma unroll
    for (int i = 0; i < 4; ++i) {
      int m = m0 + mbase + mt * 16 + lk * 4 + i;
      float* cr = C + (u64)m * HH_ + n0 + nbase + lr;
#pragma unroll
      for (int nt = 0; nt < 4; ++nt)
        __builtin_nontemporal_store(acc[mt][nt][i] + bn[nt], cr + nt * 16);
    }
  }
}

// ---------------------------------------------------------------------------
// k_scan v13 = v12 + store-side visibility fix + bounded escalation.
// r12 counters: FETCH 348->132MB (local-tier READS work, served by L2) but
// VALUBusy 3->28% (retry spin): the plain hL store lingers before becoming
// L2-visible. Fixes:
//  (a) hL store now `global_store_dword ... sc0` (coherent store -> prompt
//      L2 write-through). Tag protection bounds any semantic surprise to
//      slowness, never wrongness.
//  (b) Escalation after 2 failed local rounds (round>=3 -> mirror always);
//      caps wasted spin at 2 local rounds (r12 wasted 3 of every 4).
// Everything else identical to v12 (proven correct: tags, earlyclobber
// loads + waitcnt/sched_barrier fences, AGPR weights, LDS combine, gates).
// ---------------------------------------------------------------------------
__global__ __launch_bounds__(256, 1) void k_scan(float* __restrict__ out, const float* __restrict__ h0,
                                                 const float* __restrict__ b1, const float* __restrict__ b2,
                                                 const unsigned short* __restrict__ Wcat,
                                                 u32* __restrict__ hL, u32* __restrict__ hM) {
  __shared__ float part[16 * 4 * 65];  // [(w*4+nt)*4+i][l] stride 65
  const int tid = threadIdx.x, w = tid >> 6, l = tid & 63;
  const int lr = l & 15, lk = l >> 4;
  const int g = blockIdx.x & 7, r = blockIdx.x >> 3;
  const int bb = g * 8, jb = r * 32;
  const int koff = w * 256;

  // --- weights -> 128 AGPRs (r9-proven) ---
  bf16x8 wt[4][8];
#pragma unroll
  for (int nt = 0; nt < 4; ++nt) {
    int nrow = (nt < 2) ? (jb + nt * 16 + lr) : (HH_ + jb + (nt - 2) * 16 + lr);
    const unsigned short* wr = Wcat + (u64)nrow * HH_ + koff + lk * 8;
#pragma unroll
    for (int kk = 0; kk < 8; ++kk) wt[nt][kk] = *(const bf16x8*)(wr + kk * 32);
  }

  // --- epilogue identity: batch row b = tid>>5 (0..7), col cl = tid&31 ---
  const int b = tid >> 5, cl = tid & 31;
  const int grow = bb + b, gcol = jb + cl;
  const float bv1 = b1[gcol], bv2 = b2[gcol];
  float hold = h0[(u64)grow * HH_ + gcol];
  float* outp = out + (u64)grow * TT_ * HH_ + gcol;
  const u32 stIdx = (u32)grow * HH_ + gcol;                       // store word
  const u32 ldIdx = (u32)(bb + (lr & 7)) * HH_ + koff + lk * 8;   // load base
  const bool act = lr < 8;

  for (int t = 0; t < TT_; ++t) {
    float xpv = outp[(u64)t * HH_];  // xp prefetch (hides under tag wait)

    // ---- two-tier tagged load: 8 chunks x 8 words per active lane ----
    const u32 slotR = (u32)(t & 1) * (BB_ * HH_);
    const u32* pL = hL + slotR + ldIdx;
    const u32* pM = hM + slotR + ldIdx;
    const u32 expt = (u32)t;
    uint4 wq[16] = {};
    if (act) {
#pragma unroll
      for (int kk = 0; kk < 8; ++kk) {
        const u32* pc = pL + kk * 32;
        asm volatile("global_load_dwordx4 %0, %1, off sc0"
                     : "=&v"(wq[2 * kk]) : "v"(pc) : "memory");
        asm volatile("global_load_dwordx4 %0, %1, off offset:16 sc0"
                     : "=&v"(wq[2 * kk + 1]) : "v"(pc) : "memory");
      }
    }
    asm volatile("s_waitcnt vmcnt(0)" ::: "memory");
    __builtin_amdgcn_sched_barrier(0);

    u32 gm = 0;
    if (act) {
#pragma unroll
      for (int kk = 0; kk < 8; ++kk) {
        u32 bad = (wq[2 * kk].x ^ expt) | (wq[2 * kk].y ^ expt) |
                  (wq[2 * kk].z ^ expt) | (wq[2 * kk].w ^ expt) |
                  (wq[2 * kk + 1].x ^ expt) | (wq[2 * kk + 1].y ^ expt) |
                  (wq[2 * kk + 1].z ^ expt) | (wq[2 * kk + 1].w ^ expt);
        gm |= (u32)((bad & 0xFFFFu) != 0) << kk;
      }
    }
    int round = 0;
    while (__any((int)gm)) {
      ++round;
      const bool esc = round >= 3;  // 2 local tries, then mirror always
#pragma unroll
      for (int kk = 0; kk < 8; ++kk) {
        if (gm & (1u << kk)) {
          if (esc) {
            const u32* pm = pM + kk * 32;
            u32 m0 = __hip_atomic_load(pm + 0, __ATOMIC_RELAXED, __HIP_MEMORY_SCOPE_AGENT);
            u32 m1 = __hip_atomic_load(pm + 1, __ATOMIC_RELAXED, __HIP_MEMORY_SCOPE_AGENT);
            u32 m2 = __hip_atomic_load(pm + 2, __ATOMIC_RELAXED, __HIP_MEMORY_SCOPE_AGENT);
            u32 m3 = __hip_atomic_load(pm + 3, __ATOMIC_RELAXED, __HIP_MEMORY_SCOPE_AGENT);
            u32 m4 = __hip_atomic_load(pm + 4, __ATOMIC_RELAXED, __HIP_MEMORY_SCOPE_AGENT);
            u32 m5 = __hip_atomic_load(pm + 5, __ATOMIC_RELAXED, __HIP_MEMORY_SCOPE_AGENT);
            u32 m6 = __hip_atomic_load(pm + 6, __ATOMIC_RELAXED, __HIP_MEMORY_SCOPE_AGENT);
            u32 m7 = __hip_atomic_load(pm + 7, __ATOMIC_RELAXED, __HIP_MEMORY_SCOPE_AGENT);
            wq[2 * kk]     = make_uint4(m0, m1, m2, m3);
            wq[2 * kk + 1] = make_uint4(m4, m5, m6, m7);
          } else {
            const u32* pc = pL + kk * 32;
            asm volatile("global_load_dwordx4 %0, %1, off sc0"
                         : "=&v"(wq[2 * kk]) : "v"(pc) : "memory");
            asm volatile("global_load_dwordx4 %0, %1, off offset:16 sc0"
                         : "=&v"(wq[2 * kk + 1]) : "v"(pc) : "memory");
          }
        }
      }
      asm volatile("s_waitcnt vmcnt(0)" ::: "memory");
      __builtin_amdgcn_sched_barrier(0);
#pragma unroll
      for (int kk = 0; kk < 8; ++kk) {
        if (gm & (1u << kk)) {
          u32 bad = (wq[2 * kk].x ^ expt) | (wq[2 * kk].y ^ expt) |
                    (wq[2 * kk].z ^ expt) | (wq[2 * kk].w ^ expt) |
                    (wq[2 * kk + 1].x ^ expt) | (wq[2 * kk + 1].y ^ expt) |
                    (wq[2 * kk + 1].z ^ expt) | (wq[2 * kk + 1].w ^ expt);
          if (!(bad & 0xFFFFu)) gm &= ~(1u << kk);
        }
      }
    }

    // ---- unpack payload (high halves) -> A-frags; rows 8..15 zero; MFMA ----
    f32x4 acc[4] = {};
#pragma unroll
    for (int kk = 0; kk < 8; ++kk) {
      union { u32 u[4]; bf16x8 v; } au;
      if (act) {
        au.u[0] = __builtin_amdgcn_perm(wq[2 * kk].y, wq[2 * kk].x, 0x07060302);
        au.u[1] = __builtin_amdgcn_perm(wq[2 * kk].w, wq[2 * kk].z, 0x07060302);
        au.u[2] = __builtin_amdgcn_perm(wq[2 * kk + 1].y, wq[2 * kk + 1].x, 0x07060302);
        au.u[3] = __builtin_amdgcn_perm(wq[2 * kk + 1].w, wq[2 * kk + 1].z, 0x07060302);
      } else {
        au.u[0] = au.u[1] = au.u[2] = au.u[3] = 0u;
      }
#pragma unroll
      for (int nt = 0; nt < 4; ++nt)
        asm("v_mfma_f32_16x16x32_bf16 %0, %1, %2, %0"
            : "+v"(acc[nt]) : "v"(au.v), "a"(wt[nt][kk]));
    }
    asm volatile("s_nop 7\n\ts_nop 7\n\ts_nop 7"
                 : "+v"(acc[0]), "+v"(acc[1]), "+v"(acc[2]), "+v"(acc[3]));

    // ---- K-partials to LDS; combine; gates ----
#pragma unroll
    for (int nt = 0; nt < 4; ++nt)
#pragma unroll
      for (int i = 0; i < 4; ++i)
        part[((w * 4 + nt) * 4 + i) * 65 + l] = acc[nt][i];
    __syncthreads();

    const int nt1 = cl >> 4, jl = cl & 15;
    const int lidx = (b >> 2) * 16 + jl, ridx = b & 3;
    float v1 = 0.f, v2 = 0.f;
#pragma unroll
    for (int ww = 0; ww < 4; ++ww) {
      v1 += part[((ww * 4 + nt1) * 4 + ridx) * 65 + lidx];
      v2 += part[((ww * 4 + 2 + nt1) * 4 + ridx) * 65 + lidx];
    }
    float t1 = tanhfast(v1 + xpv + bv1);
    float t2 = tanhfast(v2 + xpv + bv2);
    float hn = t1 + hold * (t2 - t1);  // (1-h)*v1 + h*v2
    hold = hn;

    // ---- publish: tagged word, sc0 store (local, prompt L2) + LLC mirror ----
    if (t < TT_ - 1) {
      u32 word = ((u32)bf16rne(hn) << 16) | (u32)(t + 1);
      u32 so = (u32)((t + 1) & 1) * (BB_ * HH_) + stIdx;
      u32* lp = hL + so;
      asm volatile("global_store_dword %0, %1, off sc0"
                   :: "v"(lp), "v"(word) : "memory");
      __hip_atomic_store(hM + so, word, __ATOMIC_RELAXED, __HIP_MEMORY_SCOPE_AGENT);
    } else {
      out[(u64)BB_ * TT_ * HH_ + (u64)grow * HH_ + gcol] = hn;
    }
    outp[(u64)t * HH_] = hn;    // trajectory (off the handshake)
    __syncthreads();            // part[] WAR for next step
  }
}

// ---------------------------------------------------------------------------
extern "C" void kernel_launch(void* const* d_in, const int* in_sizes, int n_in,
                              void* d_out, int out_size, void* d_ws, size_t ws_size,
                              hipStream_t stream) {
  const float* x    = (const float*)d_in[0];
  const float* h0   = (const float*)d_in[1];
  const float* Wih  = (const float*)d_in[2];
  const float* bih  = (const float*)d_in[3];
  const float* Whh1 = (const float*)d_in[4];
  const float* bhh1 = (const float*)d_in[5];
  const float* Whh2 = (const float*)d_in[6];
  const float* bhh2 = (const float*)d_in[7];
  float* out = (float*)d_out;

  char* ws = (char*)d_ws;
  unsigned short* Wihb  = (unsigned short*)(ws + 0);          //  2 MiB
  unsigned short* Wcatb = (unsigned short*)(ws + 2097152);    //  4 MiB
  u32*            hL    = (u32*)(ws + 6291456);               //  512 KiB (local tier)
  u32*            hM    = (u32*)(ws + 6815744);               //  512 KiB (LLC mirror)
  unsigned short* xb    = (unsigned short*)(ws + 7340032);    //  64 MiB
  const bool fastx = ws_size >= 74448896ULL;

  hipLaunchKernelGGL(k_convert, dim3(2048), dim3(256), 0, stream,
                     x, h0, Wih, Whh1, Whh2, xb, Wihb, Wcatb, hL, hM, (int)fastx);
  if (fastx)
    hipLaunchKernelGGL((k_gemm<true>), dim3(2048), dim3(256), 0, stream,
                       xb, (const float*)nullptr, Wihb, bih, out);
  else
    hipLaunchKernelGGL((k_gemm<false>), dim3(2048), dim3(256), 0, stream,
                       (const unsigned short*)nullptr, x, Wihb, bih, out);
  hipLaunchKernelGGL(k_scan, dim3(NSCAN_BLOCKS), dim3(256), 0, stream,
                     out, h0, bhh1, bhh2, Wcatb, hL, hM);
}

// Round 14
// 2270.233 us; speedup vs baseline: 1.3294x; 1.0224x over previous
//
#include <hip/hip_runtime.h>

using u32 = unsigned int;
using u64 = unsigned long long;
using bf16x8 = __attribute__((ext_vector_type(8))) short;
using f32x4  = __attribute__((ext_vector_type(4))) float;

// Problem constants
#define BB_ 64
#define TT_ 512
#define II_ 1024
#define HH_ 1024
#define SCAN_BLOCKS 128    // 4 domains (16 batch rows) x 32 j-blocks (32 cols)
#define GEMM_BLOCKS 2048   // 256 m-tiles x 8 n-tiles
#define XP_PER_CHUNK 512u  // gemm blocks per t-chunk (64 b-tiles x 8 n-tiles)

__device__ __forceinline__ unsigned short bf16rne(float f) {
  u32 u = __float_as_uint(f);
  return (unsigned short)((u + 0x7FFFu + ((u >> 16) & 1u)) >> 16);
}
__device__ __forceinline__ u32 pk2(float a, float b) {
  u32 ua = __float_as_uint(a), ub = __float_as_uint(b);
  u32 lo = (ua + 0x7FFFu + ((ua >> 16) & 1u)) >> 16;
  u32 hi = (ub + 0x7FFFu + ((ub >> 16) & 1u)) & 0xFFFF0000u;
  return lo | hi;
}
__device__ __forceinline__ void gll16(const void* g, void* s) {
  __builtin_amdgcn_global_load_lds(
      (const __attribute__((address_space(1))) u32*)g,
      (__attribute__((address_space(3))) u32*)s, 16, 0, 0);
}
// fast tanh: 1 - 2/(exp2(2*log2e*x)+1); |err| < 1e-6, exact +-1 saturation
__device__ __forceinline__ float tanhfast(float x) {
  float e = __builtin_amdgcn_exp2f(x * 2.885390081777927f);
  return 1.0f - 2.0f / (e + 1.0f);
}

__device__ __forceinline__ void cvt4(const float* __restrict__ s, unsigned short* __restrict__ d, long long g) {
  float4 v = ((const float4*)s)[g];
  ushort4 o;
  o.x = bf16rne(v.x); o.y = bf16rne(v.y); o.z = bf16rne(v.z); o.w = bf16rne(v.w);
  ((ushort4*)d)[g] = o;
}

// ---------------------------------------------------------------------------
// k_convert (small): bf16 weights (W_ih, [W_hh1;W_hh2]), hbuf[slot0]=bf16(h0),
// flags+cnt_xp region (16 KB) = 0. NO x conversion (gemm converts inline).
// ~12.5 MB of work ≈ 6 us. Replay-safe: full rewrite each launch.
// ---------------------------------------------------------------------------
__global__ void k_convert(const float* __restrict__ h0,
                          const float* __restrict__ Wih, const float* __restrict__ Wh1,
                          const float* __restrict__ Wh2,
                          unsigned short* __restrict__ Wihb,
                          unsigned short* __restrict__ Wcatb, unsigned short* __restrict__ hbuf,
                          int* __restrict__ cnt) {
  const long long NWI = (long long)HH_ * II_ / 4;
  const long long NH0 = (long long)BB_ * HH_ / 4;
  const long long NC  = 1024;  // 4096 u32 (flags 8KB + cnt_xp + pad) via int4
  const long long total = 3 * NWI + NH0 + NC;
  for (long long g = (long long)blockIdx.x * blockDim.x + threadIdx.x; g < total;
       g += (long long)gridDim.x * blockDim.x) {
    if (g < NWI) {
      cvt4(Wih, Wihb, g);
    } else if (g < 2 * NWI) {
      cvt4(Wh1, Wcatb, g - NWI);
    } else if (g < 3 * NWI) {
      cvt4(Wh2, Wcatb + (long long)HH_ * II_, g - 2 * NWI);
    } else if (g < 3 * NWI + NH0) {
      cvt4(h0, hbuf, g - 3 * NWI);
    } else {
      ((int4*)cnt)[g - 3 * NWI - NH0] = make_int4(0, 0, 0, 0);
    }
  }
}

// ---------------------------------------------------------------------------
// GEMM role (fused): xp = x @ Wih^T + b_ih -> d_out, t-chunk ordered.
// A staged from fp32 x with INLINE bf16 convert (r1 XB=false path; same
// bf16rne as cvt4 -> xp bit-identical to the r9 pipeline). B staged from
// pre-converted bf16 Wih via global_load_lds. Tile mapping: tq = tile/64
// (t-chunk 0..3), so all 64 batch rows finish chunk 0 first. On completion:
// vmcnt drain + barrier + tid0 RELEASE agent atomicAdd on cnt_xp[tq] --
// the release emits the L2 writeback, so xp lines are clean-in-LLC before
// the counter is observable (no dirty-line writeback can clobber h later).
// ---------------------------------------------------------------------------
__device__ void gemm_role(int gb, char* smem, const float* __restrict__ xf,
                          const unsigned short* __restrict__ Wb,
                          const float* __restrict__ bias, float* __restrict__ C,
                          u32* __restrict__ cnt_xp) {
  unsigned short* ldsA = (unsigned short*)smem;            // 16 KB
  unsigned short* ldsB = (unsigned short*)(smem + 16384);  // 16 KB
  const int tid = threadIdx.x;
  const int w = tid >> 6, l = tid & 63;
  const int lr = l & 15, lk = l >> 4;
  const int tile = gb >> 3;
  const int n0 = (gb & 7) * 128;
  const int tq = tile >> 6;       // t-chunk 0..3
  const int bidx = tile & 63;     // batch row
  const int m0 = (bidx * 4 + tq) * 128;
  const int mbase = (w >> 1) * 64, nbase = (w & 1) * 64;

  f32x4 acc[4][4] = {};

  for (int kb = 0; kb < 16; ++kb) {
    const int k0 = kb * 64;
#pragma unroll
    for (int r = 0; r < 4; ++r) {
      int tb = r * 4096 + w * 1024 + l * 16;
      int row = tb >> 7;
      int p = (tb >> 4) & 7;
      int c = p ^ (row & 7);
      gll16(Wb + (u64)(n0 + row) * II_ + k0 + c * 8,
            (char*)ldsB + r * 4096 + w * 1024);
    }
    {  // A: fp32 -> bf16 inline staging (2 threads/row, 32 floats each)
      const int r = tid >> 1, ch = tid & 1;
      const float* gs = xf + (u64)(m0 + r) * II_ + k0 + ch * 32;
      float4 v[8];
#pragma unroll
      for (int q = 0; q < 8; ++q) v[q] = ((const float4*)gs)[q];
#pragma unroll
      for (int q = 0; q < 4; ++q) {
        int c = ch * 4 + q;
        int p = c ^ (r & 7);
        uint4 pk;
        pk.x = pk2(v[2 * q].x, v[2 * q].y);
        pk.y = pk2(v[2 * q].z, v[2 * q].w);
        pk.z = pk2(v[2 * q + 1].x, v[2 * q + 1].y);
        pk.w = pk2(v[2 * q + 1].z, v[2 * q + 1].w);
        *(uint4*)((char*)ldsA + r * 128 + p * 16) = pk;
      }
    }
    __syncthreads();

    bf16x8 a[4][2], b[4][2];
#pragma unroll
    for (int mt = 0; mt < 4; ++mt) {
      int row = mbase + mt * 16 + lr;
#pragma unroll
      for (int kk = 0; kk < 2; ++kk) {
        int c = kk * 4 + lk, p = c ^ (row & 7);
        a[mt][kk] = *(const bf16x8*)((const char*)ldsA + row * 128 + p * 16);
      }
    }
#pragma unroll
    for (int nt = 0; nt < 4; ++nt) {
      int row = nbase + nt * 16 + lr;
#pragma unroll
      for (int kk = 0; kk < 2; ++kk) {
        int c = kk * 4 + lk, p = c ^ (row & 7);
        b[nt][kk] = *(const bf16x8*)((const char*)ldsB + row * 128 + p * 16);
      }
    }
#pragma unroll
    for (int kk = 0; kk < 2; ++kk)
#pragma unroll
      for (int mt = 0; mt < 4; ++mt)
#pragma unroll
        for (int nt = 0; nt < 4; ++nt)
          acc[mt][nt] = __builtin_amdgcn_mfma_f32_16x16x32_bf16(a[mt][kk], b[nt][kk], acc[mt][nt], 0, 0, 0);
    __syncthreads();
  }

  float bn[4];
#pragma unroll
  for (int nt = 0; nt < 4; ++nt) bn[nt] = bias[n0 + nbase + nt * 16 + lr];
#pragma unroll
  for (int mt = 0; mt < 4; ++mt) {
#pragma unroll
    for (int i = 0; i < 4; ++i) {
      int m = m0 + mbase + mt * 16 + lk * 4 + i;
      float* cr = C + (u64)m * HH_ + n0 + nbase + lr;
#pragma unroll
      for (int nt = 0; nt < 4; ++nt) cr[nt * 16] = acc[mt][nt][i] + bn[nt];
    }
  }

  // publish chunk completion (release = L2 writeback before visibility)
  asm volatile("s_waitcnt vmcnt(0)" ::: "memory");
  __syncthreads();
  if (tid == 0)
    __hip_atomic_fetch_add(cnt_xp + tq, 1u, __ATOMIC_RELEASE, __HIP_MEMORY_SCOPE_AGENT);
}

// ---------------------------------------------------------------------------
// Scan role (fused) = r9 k_scan VERBATIM (proven best: 3.97us/step) plus a
// 4x xp-chunk gate: at t = 0/128/256/384, wait until cnt_xp[t>>7]==512
// (all xp for that t-chunk in LLC, release-flushed). First-touch argument
// makes relaxed reads safe: no scan-side cache ever held an xp line before
// its producer's release (same-XCD producers are L2-coherent; cross-XCD
// reads miss to LLC which holds the flushed data).
// ---------------------------------------------------------------------------
__device__ void scan_role(int sb, char* smem, float* __restrict__ out,
                          const float* __restrict__ h0,
                          const float* __restrict__ b1, const float* __restrict__ b2,
                          const unsigned short* __restrict__ Wcat,
                          unsigned short* __restrict__ hbuf, u32* __restrict__ flags,
                          u32* __restrict__ cnt_xp) {
  float* part = (float*)smem;  // [16*4][65] = 16.6 KB
  const int tid = threadIdx.x, w = tid >> 6, l = tid & 63;
  const int lr = l & 15, lk = l >> 4;
  const int og = sb & 31, bg = sb >> 5;
  const int jb = og * 32, bb = bg * 16;
  const int koff = w * 256;

  // --- weights -> 128 AGPRs: nt 0/1 = W_hh1 j-tiles, 2/3 = W_hh2 j-tiles ---
  bf16x8 wt[4][8];
#pragma unroll
  for (int nt = 0; nt < 4; ++nt) {
    int nrow = (nt < 2) ? (jb + nt * 16 + lr) : (HH_ + jb + (nt - 2) * 16 + lr);
    const unsigned short* wr = Wcat + (u64)nrow * HH_ + koff + lk * 8;
#pragma unroll
    for (int kk = 0; kk < 8; ++kk) wt[nt][kk] = *(const bf16x8*)(wr + kk * 32);
  }

  // --- epilogue identity: batch row b = tid&15, col pair jp = tid>>4 ---
  const int b = tid & 15, jp = tid >> 4;
  const int grow = bb + b;
  const int c0 = jb + jp * 2;
  float bv1[2] = {b1[c0], b1[c0 + 1]};
  float bv2[2] = {b2[c0], b2[c0 + 1]};
  float hold[2] = {h0[(u64)grow * HH_ + c0], h0[(u64)grow * HH_ + c0 + 1]};
  float* outp = out + (u64)grow * TT_ * HH_ + c0;

  u32* dflag = flags + bg * 512;                     // 32 flags, stride 16 u32
  const u64 ldw = ((u64)(bb + lr) * HH_ + koff + lk * 8) >> 2;
  const u64 stw = ((u64)grow * HH_ + c0) >> 1;

  for (int t = 0; t < TT_; ++t) {
    // xp-chunk gate (4x total): chunk t>>7 must be fully published
    if ((t & 127) == 0) {
      while (__hip_atomic_load(cnt_xp + (t >> 7), __ATOMIC_RELAXED, __HIP_MEMORY_SCOPE_AGENT) < XP_PER_CHUNK)
        __builtin_amdgcn_s_sleep(2);
    }

    float2 xpv = *(const float2*)(outp + (u64)t * HH_);  // xp; hides under poll

    if (t > 0) {
      if (w == 0) {
        const u32 need = (u32)t;
        while (true) {
          u32 v = (l < 32)
                      ? __hip_atomic_load(dflag + l * 16, __ATOMIC_RELAXED, __HIP_MEMORY_SCOPE_AGENT)
                      : 0xFFFFFFFFu;
          if (__all((int)(v >= need))) break;
        }
      }
      __syncthreads();  // also part[] WAR: prior combine reads done
    }

    // --- bulk pipelined h loads (relaxed agent u64 = LLC-direct), MFMA ---
    const u64* hB = (const u64*)hbuf + (u64)(t & 1) * (BB_ * HH_ / 4) + ldw;
    bf16x8 av[8];
#pragma unroll
    for (int kk = 0; kk < 8; ++kk) {
      union { u64 q[2]; bf16x8 v; } au;
      au.q[0] = __hip_atomic_load(hB + kk * 8,     __ATOMIC_RELAXED, __HIP_MEMORY_SCOPE_AGENT);
      au.q[1] = __hip_atomic_load(hB + kk * 8 + 1, __ATOMIC_RELAXED, __HIP_MEMORY_SCOPE_AGENT);
      av[kk] = au.v;
    }

    f32x4 acc[4] = {};
#pragma unroll
    for (int kk = 0; kk < 8; ++kk)
#pragma unroll
      for (int nt = 0; nt < 4; ++nt)
        asm("v_mfma_f32_16x16x32_bf16 %0, %1, %2, %0"
            : "+v"(acc[nt]) : "v"(av[kk]), "a"(wt[nt][kk]));
    // hazard fence: accs pass THROUGH the asm (r8-proven)
    asm volatile("s_nop 7\n\ts_nop 7\n\ts_nop 7"
                 : "+v"(acc[0]), "+v"(acc[1]), "+v"(acc[2]), "+v"(acc[3]));

    // --- K-partials to LDS: D[batch=lk*4+i][j=nt_tile*16+lr] ---
#pragma unroll
    for (int nt = 0; nt < 4; ++nt)
#pragma unroll
      for (int i = 0; i < 4; ++i)
        part[((w * 4 + nt) * 4 + i) * 65 + l] = acc[nt][i];
    __syncthreads();

    // --- combine + gates: thread owns (batch b, cols c0, c0+1) ---
    float hn[2];
#pragma unroll
    for (int q = 0; q < 2; ++q) {
      const int cl = jp * 2 + q;
      const int nt1 = cl >> 4, jl = cl & 15;
      const int lidx = (b >> 2) * 16 + jl, ridx = b & 3;
      float v1 = 0.f, v2 = 0.f;
#pragma unroll
      for (int ww = 0; ww < 4; ++ww) {
        v1 += part[((ww * 4 + nt1) * 4 + ridx) * 65 + lidx];
        v2 += part[((ww * 4 + 2 + nt1) * 4 + ridx) * 65 + lidx];
      }
      float xi = (q == 0) ? xpv.x : xpv.y;
      float t1 = tanhfast(v1 + xi + bv1[q]);
      float t2 = tanhfast(v2 + xi + bv2[q]);
      hn[q] = t1 + hold[q] * (t2 - t1);  // (1-h)*v1 + h*v2
      hold[q] = hn[q];
    }

    // --- publish: u32 h-store, vmcnt(0), barrier, tid0 relaxed flag ---
    if (t < TT_ - 1) {
      u32 wd = (u32)bf16rne(hn[0]) | ((u32)bf16rne(hn[1]) << 16);
      __hip_atomic_store((u32*)hbuf + (u64)((t + 1) & 1) * (BB_ * HH_ / 2) + stw, wd,
                         __ATOMIC_RELAXED, __HIP_MEMORY_SCOPE_AGENT);
      asm volatile("s_waitcnt vmcnt(0)" ::: "memory");
      __syncthreads();  // all 256 threads' h-stores are in LLC; part[] WAR
      if (tid == 0)
        __hip_atomic_store(dflag + og * 16, (u32)(t + 1), __ATOMIC_RELAXED, __HIP_MEMORY_SCOPE_AGENT);
    } else {
      *(float2*)(out + (u64)BB_ * TT_ * HH_ + (u64)grow * HH_ + c0) = make_float2(hn[0], hn[1]);
    }

    // --- fp32 trajectory store AFTER the handshake (off critical chain) ---
    *(float2*)(outp + (u64)t * HH_) = make_float2(hn[0], hn[1]);
  }
}

// ---------------------------------------------------------------------------
// k_fused: blocks 0..127 = persistent scan (dispatched first -> resident);
// blocks 128..2175 = GEMM tiles. Deadlock-free: gemm blocks have no
// dependencies (always drain -> CUs free); scan blocks only wait on gemm
// counters and each other (all 128 fit co-resident).
// ---------------------------------------------------------------------------
__global__ __launch_bounds__(256, 1) void k_fused(float* __restrict__ out,
                                                  const float* __restrict__ x,
                                                  const float* __restrict__ h0,
                                                  const float* __restrict__ bih,
                                                  const float* __restrict__ b1,
                                                  const float* __restrict__ b2,
                                                  const unsigned short* __restrict__ Wihb,
                                                  const unsigned short* __restrict__ Wcat,
                                                  unsigned short* __restrict__ hbuf,
                                                  u32* __restrict__ flags,
                                                  u32* __restrict__ cnt_xp) {
  __shared__ __align__(16) char smem[32768];
  if (blockIdx.x < SCAN_BLOCKS)
    scan_role(blockIdx.x, smem, out, h0, b1, b2, Wcat, hbuf, flags, cnt_xp);
  else
    gemm_role(blockIdx.x - SCAN_BLOCKS, smem, x, Wihb, bih, out, cnt_xp);
}

// ---------------------------------------------------------------------------
extern "C" void kernel_launch(void* const* d_in, const int* in_sizes, int n_in,
                              void* d_out, int out_size, void* d_ws, size_t ws_size,
                              hipStream_t stream) {
  const float* x    = (const float*)d_in[0];
  const float* h0   = (const float*)d_in[1];
  const float* Wih  = (const float*)d_in[2];
  const float* bih  = (const float*)d_in[3];
  const float* Whh1 = (const float*)d_in[4];
  const float* bhh1 = (const float*)d_in[5];
  const float* Whh2 = (const float*)d_in[6];
  const float* bhh2 = (const float*)d_in[7];
  float* out = (float*)d_out;

  char* ws = (char*)d_ws;
  unsigned short* Wihb  = (unsigned short*)(ws + 0);          //  2 MiB
  unsigned short* Wcatb = (unsigned short*)(ws + 2097152);    //  4 MiB
  unsigned short* hbuf  = (unsigned short*)(ws + 6291456);    //  256 KiB (2 bf16 buffers)
  int*            cnt   = (int*)(ws + 6553600);               //  16 KiB: flags 8KB | cnt_xp
  u32*            flags = (u32*)cnt;
  u32*            cnt_xp = flags + 2048;                      //  4 chunk counters

  hipLaunchKernelGGL(k_convert, dim3(1024), dim3(256), 0, stream,
                     h0, Wih, Whh1, Whh2, Wihb, Wcatb, hbuf, cnt);
  hipLaunchKernelGGL(k_fused, dim3(SCAN_BLOCKS + GEMM_BLOCKS), dim3(256), 0, stream,
                     out, x, h0, bih, bhh1, bhh2, Wihb, Wcatb, hbuf, flags, cnt_xp);
}

// Round 15
// 2186.516 us; speedup vs baseline: 1.3803x; 1.0383x over previous
//
#include <hip/hip_runtime.h>

using u32 = unsigned int;
using u64 = unsigned long long;
using bf16x8 = __attribute__((ext_vector_type(8))) short;
using f32x4  = __attribute__((ext_vector_type(4))) float;

// Problem constants
#define BB_ 64
#define TT_ 512
#define II_ 1024
#define HH_ 1024
#define NSCAN_BLOCKS 128   // 4 domains (16 batch rows) x 32 j-blocks (32 cols)

__device__ __forceinline__ unsigned short bf16rne(float f) {
  u32 u = __float_as_uint(f);
  return (unsigned short)((u + 0x7FFFu + ((u >> 16) & 1u)) >> 16);
}
__device__ __forceinline__ u32 pk2(float a, float b) {
  u32 ua = __float_as_uint(a), ub = __float_as_uint(b);
  u32 lo = (ua + 0x7FFFu + ((ua >> 16) & 1u)) >> 16;
  u32 hi = (ub + 0x7FFFu + ((ub >> 16) & 1u)) & 0xFFFF0000u;
  return lo | hi;
}
__device__ __forceinline__ void gll16(const void* g, void* s) {
  __builtin_amdgcn_global_load_lds(
      (const __attribute__((address_space(1))) u32*)g,
      (__attribute__((address_space(3))) u32*)s, 16, 0, 0);
}
// fast tanh: 1 - 2/(exp2(2*log2e*x)+1); |err| < 1e-6, exact +-1 saturation
__device__ __forceinline__ float tanhfast(float x) {
  float e = __builtin_amdgcn_exp2f(x * 2.885390081777927f);
  return 1.0f - 2.0f / (e + 1.0f);
}

__device__ __forceinline__ void cvt4(const float* __restrict__ s, unsigned short* __restrict__ d, long long g) {
  float4 v = ((const float4*)s)[g];
  ushort4 o;
  o.x = bf16rne(v.x); o.y = bf16rne(v.y); o.z = bf16rne(v.z); o.w = bf16rne(v.w);
  ((ushort4*)d)[g] = o;
}

// ---------------------------------------------------------------------------
// k_convert (r1-proven): bf16 copies of x / W_ih / [W_hh1;W_hh2],
// hbuf[parity0]=bf16(h0), flags (16KB) = 0. Replay-safe (full rewrite).
// ---------------------------------------------------------------------------
__global__ void k_convert(const float* __restrict__ x, const float* __restrict__ h0,
                          const float* __restrict__ Wih, const float* __restrict__ Wh1,
                          const float* __restrict__ Wh2,
                          unsigned short* __restrict__ xb, unsigned short* __restrict__ Wihb,
                          unsigned short* __restrict__ Wcatb, unsigned short* __restrict__ hbuf,
                          int* __restrict__ cnt, int do_x) {
  const long long NWI = (long long)HH_ * II_ / 4;
  const long long NH0 = (long long)BB_ * HH_ / 4;
  const long long NC  = 1024;  // 4096 flag u32s via int4 (16 KB)
  const long long NX  = do_x ? ((long long)BB_ * TT_ * II_ / 4) : 0;
  const long long total = 3 * NWI + NH0 + NC + NX;
  for (long long g = (long long)blockIdx.x * blockDim.x + threadIdx.x; g < total;
       g += (long long)gridDim.x * blockDim.x) {
    if (g < NWI) {
      cvt4(Wih, Wihb, g);
    } else if (g < 2 * NWI) {
      cvt4(Wh1, Wcatb, g - NWI);
    } else if (g < 3 * NWI) {
      cvt4(Wh2, Wcatb + (long long)HH_ * II_, g - 2 * NWI);
    } else if (g < 3 * NWI + NH0) {
      cvt4(h0, hbuf, g - 3 * NWI);
    } else if (g < 3 * NWI + NH0 + NC) {
      ((int4*)cnt)[g - 3 * NWI - NH0] = make_int4(0, 0, 0, 0);
    } else {
      cvt4(x, xb, g - (3 * NWI + NH0 + NC));
    }
  }
}

// ---------------------------------------------------------------------------
// k_gemm: xp = x @ Wih^T + b_ih, written into d_out. (unchanged, verified)
// ---------------------------------------------------------------------------
template <bool XB>
__global__ __launch_bounds__(256) void k_gemm(const unsigned short* __restrict__ xbg,
                                              const float* __restrict__ xf,
                                              const unsigned short* __restrict__ Wb,
                                              const float* __restrict__ bias,
                                              float* __restrict__ C) {
  __shared__ __align__(16) unsigned short ldsA[128 * 64];
  __shared__ __align__(16) unsigned short ldsB[128 * 64];
  const int tid = threadIdx.x;
  const int w = tid >> 6, l = tid & 63;
  const int lr = l & 15, lk = l >> 4;
  const int n0 = (blockIdx.x & 7) * 128;
  const int m0 = (blockIdx.x >> 3) * 128;
  const int mbase = (w >> 1) * 64, nbase = (w & 1) * 64;

  f32x4 acc[4][4] = {};

  for (int kb = 0; kb < 16; ++kb) {
    const int k0 = kb * 64;
#pragma unroll
    for (int r = 0; r < 4; ++r) {
      int tb = r * 4096 + w * 1024 + l * 16;
      int row = tb >> 7;
      int p = (tb >> 4) & 7;
      int c = p ^ (row & 7);
      gll16(Wb + (u64)(n0 + row) * II_ + k0 + c * 8,
            (char*)ldsB + r * 4096 + w * 1024);
    }
    if constexpr (XB) {
#pragma unroll
      for (int r = 0; r < 4; ++r) {
        int tb = r * 4096 + w * 1024 + l * 16;
        int row = tb >> 7;
        int p = (tb >> 4) & 7;
        int c = p ^ (row & 7);
        gll16(xbg + (u64)(m0 + row) * II_ + k0 + c * 8,
              (char*)ldsA + r * 4096 + w * 1024);
      }
    } else {
      const int r = tid >> 1, ch = tid & 1;
      const float* gs = xf + (u64)(m0 + r) * II_ + k0 + ch * 32;
      float4 v[8];
#pragma unroll
      for (int q = 0; q < 8; ++q) v[q] = ((const float4*)gs)[q];
#pragma unroll
      for (int q = 0; q < 4; ++q) {
        int c = ch * 4 + q;
        int p = c ^ (r & 7);
        uint4 pk;
        pk.x = pk2(v[2 * q].x, v[2 * q].y);
        pk.y = pk2(v[2 * q].z, v[2 * q].w);
        pk.z = pk2(v[2 * q + 1].x, v[2 * q + 1].y);
        pk.w = pk2(v[2 * q + 1].z, v[2 * q + 1].w);
        *(uint4*)((char*)ldsA + r * 128 + p * 16) = pk;
      }
    }
    __syncthreads();

    bf16x8 a[4][2], b[4][2];
#pragma unroll
    for (int mt = 0; mt < 4; ++mt) {
      int row = mbase + mt * 16 + lr;
#pragma unroll
      for (int kk = 0; kk < 2; ++kk) {
        int c = kk * 4 + lk, p = c ^ (row & 7);
        a[mt][kk] = *(const bf16x8*)((const char*)ldsA + row * 128 + p * 16);
      }
    }
#pragma unroll
    for (int nt = 0; nt < 4; ++nt) {
      int row = nbase + nt * 16 + lr;
#pragma unroll
      for (int kk = 0; kk < 2; ++kk) {
        int c = kk * 4 + lk, p = c ^ (row & 7);
        b[nt][kk] = *(const bf16x8*)((const char*)ldsB + row * 128 + p * 16);
      }
    }
#pragma unroll
    for (int kk = 0; kk < 2; ++kk)
#pragma unroll
      for (int mt = 0; mt < 4; ++mt)
#pragma unroll
        for (int nt = 0; nt < 4; ++nt)
          acc[mt][nt] = __builtin_amdgcn_mfma_f32_16x16x32_bf16(a[mt][kk], b[nt][kk], acc[mt][nt], 0, 0, 0);
    __syncthreads();
  }

  float bn[4];
#pragma unroll
  for (int nt = 0; nt < 4; ++nt) bn[nt] = bias[n0 + nbase + nt * 16 + lr];
#pragma unroll
  for (int mt = 0; mt < 4; ++mt) {
#pragma unroll
    for (int i = 0; i < 4; ++i) {
      int m = m0 + mbase + mt * 16 + lk * 4 + i;
      float* cr = C + (u64)m * HH_ + n0 + nbase + lr;
#pragma unroll
      for (int nt = 0; nt < 4; ++nt) cr[nt * 16] = acc[mt][nt][i] + bn[nt];
    }
  }
}

// ---------------------------------------------------------------------------
// k_scan v9 (best measured: 3.97us/step, total 2187):
//  - r2-proven protocol: wave0 polls 32 domain flags -> barrier; bulk
//    pipelined relaxed-agent u64 h loads; publish = h-store, vmcnt(0),
//    barrier, tid0 relaxed flag store. Equality flags + double buffer.
//  - weights AGPR-pinned via asm MFMA ("a" B-operand);
//  - direct u32 h-store epilogue mapping (batch=tid&15, colpair=tid>>4);
//  - flags padded to 64B (32 LLC lines/domain).
// ---------------------------------------------------------------------------
__global__ __launch_bounds__(256, 1) void k_scan(float* __restrict__ out, const float* __restrict__ h0,
                                                 const float* __restrict__ b1, const float* __restrict__ b2,
                                                 const unsigned short* __restrict__ Wcat,
                                                 unsigned short* __restrict__ hbuf, u32* __restrict__ flags) {
  __shared__ float part[16 * 4 * 65];  // [(w*4+nt)*4+i][l] stride 65 = 16.6KB
  const int tid = threadIdx.x, w = tid >> 6, l = tid & 63;
  const int lr = l & 15, lk = l >> 4;
  const int og = blockIdx.x & 31, bg = blockIdx.x >> 5;
  const int jb = og * 32, bb = bg * 16;
  const int koff = w * 256;

  // --- weights -> 128 AGPRs: nt 0/1 = W_hh1 j-tiles, 2/3 = W_hh2 j-tiles ---
  bf16x8 wt[4][8];
#pragma unroll
  for (int nt = 0; nt < 4; ++nt) {
    int nrow = (nt < 2) ? (jb + nt * 16 + lr) : (HH_ + jb + (nt - 2) * 16 + lr);
    const unsigned short* wr = Wcat + (u64)nrow * HH_ + koff + lk * 8;
#pragma unroll
    for (int kk = 0; kk < 8; ++kk) wt[nt][kk] = *(const bf16x8*)(wr + kk * 32);
  }

  // --- epilogue identity: batch row b = tid&15, col pair jp = tid>>4 ---
  const int b = tid & 15, jp = tid >> 4;
  const int grow = bb + b;
  const int c0 = jb + jp * 2;          // global col of q=0
  float bv1[2] = {b1[c0], b1[c0 + 1]};
  float bv2[2] = {b2[c0], b2[c0 + 1]};
  float hold[2] = {h0[(u64)grow * HH_ + c0], h0[(u64)grow * HH_ + c0 + 1]};
  float* outp = out + (u64)grow * TT_ * HH_ + c0;   // + t*HH_ per step

  u32* dflag = flags + bg * 512;                     // 32 flags, stride 16 u32 (64B)
  const u64 ldw = ((u64)(bb + lr) * HH_ + koff + lk * 8) >> 2;  // u64 idx, h load
  const u64 stw = ((u64)grow * HH_ + c0) >> 1;                  // u32 idx, h store

  for (int t = 0; t < TT_; ++t) {
    float2 xpv = *(const float2*)(outp + (u64)t * HH_);  // xp; hides under poll

    if (t > 0) {
      if (w == 0) {
        const u32 need = (u32)t;
        while (true) {
          u32 v = (l < 32)
                      ? __hip_atomic_load(dflag + l * 16, __ATOMIC_RELAXED, __HIP_MEMORY_SCOPE_AGENT)
                      : 0xFFFFFFFFu;
          if (__all((int)(v >= need))) break;
        }
      }
      __syncthreads();  // also part[] WAR: prior combine reads done
    }

    // --- bulk pipelined h loads (relaxed agent u64 = LLC-direct), MFMA ---
    const u64* hB = (const u64*)hbuf + (u64)(t & 1) * (BB_ * HH_ / 4) + ldw;
    bf16x8 av[8];
#pragma unroll
    for (int kk = 0; kk < 8; ++kk) {
      union { u64 q[2]; bf16x8 v; } au;
      au.q[0] = __hip_atomic_load(hB + kk * 8,     __ATOMIC_RELAXED, __HIP_MEMORY_SCOPE_AGENT);
      au.q[1] = __hip_atomic_load(hB + kk * 8 + 1, __ATOMIC_RELAXED, __HIP_MEMORY_SCOPE_AGENT);
      av[kk] = au.v;
    }

    f32x4 acc[4] = {};
#pragma unroll
    for (int kk = 0; kk < 8; ++kk)
#pragma unroll
      for (int nt = 0; nt < 4; ++nt)
        asm("v_mfma_f32_16x16x32_bf16 %0, %1, %2, %0"
            : "+v"(acc[nt]) : "v"(av[kk]), "a"(wt[nt][kk]));
    // hazard fence: accs pass THROUGH the asm (r8-proven)
    asm volatile("s_nop 7\n\ts_nop 7\n\ts_nop 7"
                 : "+v"(acc[0]), "+v"(acc[1]), "+v"(acc[2]), "+v"(acc[3]));

    // --- K-partials to LDS: D[batch=lk*4+i][j=nt_tile*16+lr] ---
#pragma unroll
    for (int nt = 0; nt < 4; ++nt)
#pragma unroll
      for (int i = 0; i < 4; ++i)
        part[((w * 4 + nt) * 4 + i) * 65 + l] = acc[nt][i];
    __syncthreads();

    // --- combine + gates: thread owns (batch b, cols c0, c0+1) ---
    float hn[2];
#pragma unroll
    for (int q = 0; q < 2; ++q) {
      const int cl = jp * 2 + q;            // local col 0..31
      const int nt1 = cl >> 4, jl = cl & 15;
      const int lidx = (b >> 2) * 16 + jl, ridx = b & 3;
      float v1 = 0.f, v2 = 0.f;
#pragma unroll
      for (int ww = 0; ww < 4; ++ww) {
        v1 += part[((ww * 4 + nt1) * 4 + ridx) * 65 + lidx];
        v2 += part[((ww * 4 + 2 + nt1) * 4 + ridx) * 65 + lidx];
      }
      float xi = (q == 0) ? xpv.x : xpv.y;
      float t1 = tanhfast(v1 + xi + bv1[q]);
      float t2 = tanhfast(v2 + xi + bv2[q]);
      hn[q] = t1 + hold[q] * (t2 - t1);  // (1-h)*v1 + h*v2
      hold[q] = hn[q];
    }

    // --- publish: u32 h-store, vmcnt(0), barrier, tid0 relaxed flag ---
    if (t < TT_ - 1) {
      u32 wd = (u32)bf16rne(hn[0]) | ((u32)bf16rne(hn[1]) << 16);
      __hip_atomic_store((u32*)hbuf + (u64)((t + 1) & 1) * (BB_ * HH_ / 2) + stw, wd,
                         __ATOMIC_RELAXED, __HIP_MEMORY_SCOPE_AGENT);
      asm volatile("s_waitcnt vmcnt(0)" ::: "memory");
      __syncthreads();  // all 256 threads' h-stores are in LLC; part[] WAR
      if (tid == 0)
        __hip_atomic_store(dflag + og * 16, (u32)(t + 1), __ATOMIC_RELAXED, __HIP_MEMORY_SCOPE_AGENT);
    } else {
      *(float2*)(out + (u64)BB_ * TT_ * HH_ + (u64)grow * HH_ + c0) = make_float2(hn[0], hn[1]);
    }

    // --- fp32 trajectory store AFTER the handshake (off critical chain) ---
    *(float2*)(outp + (u64)t * HH_) = make_float2(hn[0], hn[1]);
  }
}

// ---------------------------------------------------------------------------
extern "C" void kernel_launch(void* const* d_in, const int* in_sizes, int n_in,
                              void* d_out, int out_size, void* d_ws, size_t ws_size,
                              hipStream_t stream) {
  const float* x    = (const float*)d_in[0];
  const float* h0   = (const float*)d_in[1];
  const float* Wih  = (const float*)d_in[2];
  const float* bih  = (const float*)d_in[3];
  const float* Whh1 = (const float*)d_in[4];
  const float* bhh1 = (const float*)d_in[5];
  const float* Whh2 = (const float*)d_in[6];
  const float* bhh2 = (const float*)d_in[7];
  float* out = (float*)d_out;

  char* ws = (char*)d_ws;
  unsigned short* Wihb  = (unsigned short*)(ws + 0);          //  2 MiB
  unsigned short* Wcatb = (unsigned short*)(ws + 2097152);    //  4 MiB
  unsigned short* hbuf  = (unsigned short*)(ws + 6291456);    //  256 KiB (2 bf16 buffers)
  int*            cnt   = (int*)(ws + 6553600);               //  16 KiB (padded flags)
  unsigned short* xb    = (unsigned short*)(ws + 6569984);    //  64 MiB
  const bool fastx = ws_size >= 73678848ULL;

  hipLaunchKernelGGL(k_convert, dim3(2048), dim3(256), 0, stream,
                     x, h0, Wih, Whh1, Whh2, xb, Wihb, Wcatb, hbuf, cnt, (int)fastx);
  if (fastx)
    hipLaunchKernelGGL((k_gemm<true>), dim3(2048), dim3(256), 0, stream,
                       xb, (const float*)nullptr, Wihb, bih, out);
  else
    hipLaunchKernelGGL((k_gemm<false>), dim3(2048), dim3(256), 0, stream,
                       (const unsigned short*)nullptr, x, Wihb, bih, out);
  hipLaunchKernelGGL(k_scan, dim3(NSCAN_BLOCKS), dim3(256), 0, stream,
                     out, h0, bhh1, bhh2, Wcatb, hbuf, (u32*)cnt);
}